// Round 7
// baseline (240.537 us; speedup 1.0000x reference)
//
#include <hip/hip_runtime.h>

#define F_IN 128
#define F_ALL 128
#define F_HOP 64

#define RPB_BITS 7
#define RPB 128            // rows per bucket
#define KB_MAX 1024        // max buckets (N <= 131072)
#define NBLK_BIN 512       // blocks for hist/bin kernels (== threads in blockscan)
#define ECAP 2048          // LDS edge-cache slots per bucket in pass kernels (16 KB)

typedef unsigned int uint;
typedef unsigned short ushort;
typedef __attribute__((ext_vector_type(8))) short short8v;
typedef __attribute__((ext_vector_type(4))) float float4v;

// ---------------------------------------------------------------- helpers
__device__ __forceinline__ uint pack_bf16(float lo, float hi) {
    uint ul = __float_as_uint(lo), uh = __float_as_uint(hi);
    ul += 0x7FFFu + ((ul >> 16) & 1u);
    uh += 0x7FFFu + ((uh >> 16) & 1u);
    return (ul >> 16) | (uh & 0xFFFF0000u);
}
__device__ __forceinline__ float bf_lo(uint h) { return __uint_as_float(h << 16); }
__device__ __forceinline__ float bf_hi(uint h) { return __uint_as_float(h & 0xFFFF0000u); }

// ---------------------------------------------------------------- MFMA GEMM + bf16 pack, fused with
// bucket histogram (independent work: hist blocks ride along after the gemm blocks).
__global__ __launch_bounds__(256) void gemm_hist_kernel(
    const float* __restrict__ x, const float* __restrict__ W0,
    const float* __restrict__ W1, uint* __restrict__ H2,
    const int* __restrict__ ei, int* __restrict__ bhist,
    int N, int E, int K, int gemmBlocks) {
    __shared__ ushort Wlds[16384];    // 32 KB (gemm); aliased as int[] by hist

    if ((int)blockIdx.x >= gemmBlocks) {
        // ---------------- histogram branch
        int* h = (int*)Wlds;
        const int hb = blockIdx.x - gemmBlocks;
        for (int i = threadIdx.x; i < K; i += 256) h[i] = 0;
        __syncthreads();
        const int chunk = (E + NBLK_BIN - 1) / NBLK_BIN;
        const int s = hb * chunk;
        const int e = min(s + chunk, E);
        for (int j = s + threadIdx.x; j < e; j += 256)
            atomicAdd(&h[__builtin_nontemporal_load(ei + j) >> RPB_BITS], 1);
        __syncthreads();
        for (int i = threadIdx.x; i < K; i += 256)
            bhist[hb * KB_MAX + i] = h[i];
        return;
    }

    // ---------------- gemm branch
    {
        const int t = threadIdx.x;
        #pragma unroll
        for (int i = 0; i < 8; ++i) {
            const int e    = t + 256 * i;
            const int lane = e & 63;
            const int tile = e >> 6;
            const int kt   = tile >> 3;
            const int nt   = tile & 7;
            const int k0   = kt * 32 + (lane >> 4) * 8;
            const int n    = nt * 16 + (lane & 15);
            const float* src = (n < 64) ? (W0 + n) : (W1 + (n - 64));
            float v[8];
            #pragma unroll
            for (int j = 0; j < 8; ++j) v[j] = src[(size_t)(k0 + j) * F_HOP];
            uint4 o;
            o.x = pack_bf16(v[0], v[1]);
            o.y = pack_bf16(v[2], v[3]);
            o.z = pack_bf16(v[4], v[5]);
            o.w = pack_bf16(v[6], v[7]);
            *((uint4*)Wlds + e) = o;
        }
    }
    __syncthreads();

    const int wv   = threadIdx.x >> 6;
    const int lane = threadIdx.x & 63;
    const int rbase = blockIdx.x * 64 + wv * 16;
    if (rbase >= N) return;

    const int m    = lane & 15;
    const int quad = lane >> 4;
    const float* xrow = x + (size_t)(rbase + m) * F_IN + quad * 8;

    float4v acc[8];
    #pragma unroll
    for (int t = 0; t < 8; ++t) acc[t] = (float4v){0.f, 0.f, 0.f, 0.f};

    #pragma unroll
    for (int kt = 0; kt < 4; ++kt) {
        const float4v xa = __builtin_nontemporal_load((const float4v*)(xrow + kt * 32));
        const float4v xb = __builtin_nontemporal_load((const float4v*)(xrow + kt * 32 + 4));
        union { uint4 u; short8v s; } av;
        av.u.x = pack_bf16(xa[0], xa[1]);
        av.u.y = pack_bf16(xa[2], xa[3]);
        av.u.z = pack_bf16(xb[0], xb[1]);
        av.u.w = pack_bf16(xb[2], xb[3]);
        #pragma unroll
        for (int nt = 0; nt < 8; ++nt) {
            union { uint4 u; short8v s; } bv;
            bv.u = *((const uint4*)Wlds + (kt * 8 + nt) * 64 + lane);
            acc[nt] = __builtin_amdgcn_mfma_f32_16x16x32_bf16(av.s, bv.s, acc[nt], 0, 0, 0);
        }
    }

    #pragma unroll
    for (int t = 0; t < 4; ++t) {
        #pragma unroll
        for (int i = 0; i < 4; ++i) {
            const int r = rbase + quad * 4 + i;
            H2[(size_t)r * F_HOP + t * 16 + m] = pack_bf16(acc[t][i], acc[t + 4][i]);
        }
    }
}

// ---------------------------------------------------------------- stage 2: per-bucket scan of per-block
// counts (grid = K blocks, NBLK_BIN=512 threads). Converts bhist[blk][b] in place into the
// exclusive offset of block blk RELATIVE to bucket b's start; writes bucket total to btot[b].
__global__ __launch_bounds__(512) void blockscan_kernel(
    int* __restrict__ bhist, int* __restrict__ btot) {
    __shared__ int wsum[8];
    const int b = blockIdx.x;
    const int t = threadIdx.x;                  // = source block index
    const int s = bhist[t * KB_MAX + b];
    int v = s;
    #pragma unroll
    for (int d = 1; d < 64; d <<= 1) {
        int u = __shfl_up(v, (unsigned)d, 64);
        if ((t & 63) >= d) v += u;
    }
    if ((t & 63) == 63) wsum[t >> 6] = v;
    __syncthreads();
    int off = 0;
    #pragma unroll
    for (int i = 0; i < 8; ++i) if (i < (t >> 6)) off += wsum[i];
    bhist[t * KB_MAX + b] = off + v - s;        // exclusive, bucket-relative
    if (t == 511) btot[b] = off + v;            // bucket total
}

// ---------------------------------------------------------------- stage 3: direct binned scatter
// bbase (exclusive scan of btot over K <= 1024 buckets) recomputed per-block in LDS.
// Block 0 publishes bbase[] for the pass kernels.
// payload: word0 = col | (r_local << 17), word1 = val fp32
__global__ __launch_bounds__(256) void bin_kernel(
    const int* __restrict__ ei, const float* __restrict__ ea,
    const int* __restrict__ bloc, const int* __restrict__ btot,
    int* __restrict__ bbase_g, int2* __restrict__ gbuf, int E, int K) {
    __shared__ int bb[KB_MAX];
    __shared__ int cur[KB_MAX];
    __shared__ int wsum[4];
    const int t = threadIdx.x;
    // quad-scan over K entries with 256 threads
    const int i0 = 4 * t;
    const int c0 = (i0     < K) ? btot[i0]     : 0;
    const int c1 = (i0 + 1 < K) ? btot[i0 + 1] : 0;
    const int c2 = (i0 + 2 < K) ? btot[i0 + 2] : 0;
    const int c3 = (i0 + 3 < K) ? btot[i0 + 3] : 0;
    const int s = c0 + c1 + c2 + c3;
    int v = s;
    #pragma unroll
    for (int d = 1; d < 64; d <<= 1) {
        int u = __shfl_up(v, (unsigned)d, 64);
        if ((t & 63) >= d) v += u;
    }
    if ((t & 63) == 63) wsum[t >> 6] = v;
    __syncthreads();
    {
        int off = 0;
        #pragma unroll
        for (int i = 0; i < 4; ++i) if (i < (t >> 6)) off += wsum[i];
        const int excl = off + v - s;
        if (i0     < K) bb[i0]     = excl;
        if (i0 + 1 < K) bb[i0 + 1] = excl + c0;
        if (i0 + 2 < K) bb[i0 + 2] = excl + c0 + c1;
        if (i0 + 3 < K) bb[i0 + 3] = excl + c0 + c1 + c2;
    }
    __syncthreads();
    if (blockIdx.x == 0) {
        for (int i = t; i < K; i += 256) bbase_g[i] = bb[i];
        if (t == 0) bbase_g[K] = E;
    }
    for (int i = t; i < K; i += 256)
        cur[i] = bb[i] + bloc[blockIdx.x * KB_MAX + i];
    __syncthreads();
    const int chunk = (E + NBLK_BIN - 1) / NBLK_BIN;
    const int s0 = blockIdx.x * chunk;
    const int e0 = min(s0 + chunk, E);
    for (int j = s0 + t; j < e0; j += 256) {
        const int r = __builtin_nontemporal_load(ei + j);
        const int c = __builtin_nontemporal_load(ei + E + j);
        const int vv = __float_as_int(__builtin_nontemporal_load(ea + j));
        const int b = r >> RPB_BITS;
        const int gp = atomicAdd(&cur[b], 1);
        gbuf[gp] = make_int2(c | ((r & (RPB - 1)) << 17), vv);
    }
}

// ---------------------------------------------------------------- pass 1 (fused in-LDS sort)
// One block per bucket (RPB=128 rows). Load the bucket's gbuf segment to LDS, count/scan/place
// by local row, then per-row gather loop identical to the proven structure (4 rows per wave,
// 16 lanes/row, uint4 per lane -> 16 edge-gathers in flight/wave). Overflow beyond ECAP is
// handled by a (normally empty) global tail scan for correctness on any input.
__global__ __launch_bounds__(512) void pass1_kernel(
    const int* __restrict__ bbase, const int2* __restrict__ gbuf,
    const uint* __restrict__ H2,
    const float* __restrict__ b0, const float* __restrict__ fc0,
    const float* __restrict__ bf0,
    float* __restrict__ out, ushort* __restrict__ T16,
    float* __restrict__ dg1, int N) {
    __shared__ int2 ebuf[ECAP];      // 16 KB
    __shared__ int cnt[RPB];
    __shared__ int rp[RPB + 1];
    __shared__ int wsum2[2];
    const int t = threadIdx.x;
    const int b = blockIdx.x;
    const int bstart = bbase[b];
    const int m = bbase[b + 1] - bstart;
    const int mc = (m < ECAP) ? m : ECAP;
    const int row0 = b << RPB_BITS;

    if (t < RPB) cnt[t] = 0;
    __syncthreads();
    for (int j = t; j < mc; j += 512) {
        const int2 p = gbuf[bstart + j];
        ebuf[j] = p;
        atomicAdd(&cnt[(p.x >> 17) & (RPB - 1)], 1);
    }
    __syncthreads();
    int sv = 0, vv = 0;
    if (t < RPB) {
        sv = cnt[t];
        vv = sv;
        #pragma unroll
        for (int d = 1; d < 64; d <<= 1) {
            int u = __shfl_up(vv, (unsigned)d, 64);
            if ((t & 63) >= d) vv += u;
        }
        if ((t & 63) == 63) wsum2[t >> 6] = vv;
    }
    __syncthreads();
    if (t < RPB) rp[t] = ((t >= 64) ? wsum2[0] : 0) + vv - sv;
    if (t == 0) rp[RPB] = mc;
    __syncthreads();
    if (t < RPB) cnt[t] = rp[t];     // placement cursor
    __syncthreads();
    int2 pr[4]; int pp[4]; bool pvld[4];
    #pragma unroll
    for (int k2 = 0; k2 < 4; ++k2) {
        const int j = t + 512 * k2;
        pvld[k2] = (j < mc);
        if (pvld[k2]) {
            pr[k2] = ebuf[j];
            pp[k2] = atomicAdd(&cnt[(pr[k2].x >> 17) & (RPB - 1)], 1);
        }
    }
    __syncthreads();
    #pragma unroll
    for (int k2 = 0; k2 < 4; ++k2)
        if (pvld[k2]) ebuf[pp[k2]] = pr[k2];
    __syncthreads();

    const int l  = t & 15;
    const int g  = t >> 4;           // 0..31
    const int f0 = l * 4;
    const uint* __restrict__ H2b = H2 + f0;

    for (int k = 0; k < 4; ++k) {
        const int lr = g * 4 + k;
        const int r = row0 + lr;
        if (r >= N) break;
        const int jb = rp[lr], je = rp[lr + 1];

        float s00 = 0.f, s01 = 0.f, s02 = 0.f, s03 = 0.f;   // hop0 (lo)
        float s10 = 0.f, s11 = 0.f, s12 = 0.f, s13 = 0.f;   // hop1 (hi)
        float d = 0.f;
        int j = jb;
        for (; j + 4 <= je; j += 4) {
            const int2 e0 = ebuf[j], e1 = ebuf[j + 1], e2 = ebuf[j + 2], e3 = ebuf[j + 3];
            const uint4 h0 = *(const uint4*)(H2b + (size_t)(e0.x & 0x1FFFF) * F_HOP);
            const uint4 h1 = *(const uint4*)(H2b + (size_t)(e1.x & 0x1FFFF) * F_HOP);
            const uint4 h2 = *(const uint4*)(H2b + (size_t)(e2.x & 0x1FFFF) * F_HOP);
            const uint4 h3 = *(const uint4*)(H2b + (size_t)(e3.x & 0x1FFFF) * F_HOP);
            const float v0 = __int_as_float(e0.y), v1 = __int_as_float(e1.y);
            const float v2 = __int_as_float(e2.y), v3 = __int_as_float(e3.y);
            d += (v0 + v1) + (v2 + v3);
            s00 = fmaf(v0, bf_lo(h0.x), s00); s10 = fmaf(v0, bf_hi(h0.x), s10);
            s01 = fmaf(v0, bf_lo(h0.y), s01); s11 = fmaf(v0, bf_hi(h0.y), s11);
            s02 = fmaf(v0, bf_lo(h0.z), s02); s12 = fmaf(v0, bf_hi(h0.z), s12);
            s03 = fmaf(v0, bf_lo(h0.w), s03); s13 = fmaf(v0, bf_hi(h0.w), s13);
            s00 = fmaf(v1, bf_lo(h1.x), s00); s10 = fmaf(v1, bf_hi(h1.x), s10);
            s01 = fmaf(v1, bf_lo(h1.y), s01); s11 = fmaf(v1, bf_hi(h1.y), s11);
            s02 = fmaf(v1, bf_lo(h1.z), s02); s12 = fmaf(v1, bf_hi(h1.z), s12);
            s03 = fmaf(v1, bf_lo(h1.w), s03); s13 = fmaf(v1, bf_hi(h1.w), s13);
            s00 = fmaf(v2, bf_lo(h2.x), s00); s10 = fmaf(v2, bf_hi(h2.x), s10);
            s01 = fmaf(v2, bf_lo(h2.y), s01); s11 = fmaf(v2, bf_hi(h2.y), s11);
            s02 = fmaf(v2, bf_lo(h2.z), s02); s12 = fmaf(v2, bf_hi(h2.z), s12);
            s03 = fmaf(v2, bf_lo(h2.w), s03); s13 = fmaf(v2, bf_hi(h2.w), s13);
            s00 = fmaf(v3, bf_lo(h3.x), s00); s10 = fmaf(v3, bf_hi(h3.x), s10);
            s01 = fmaf(v3, bf_lo(h3.y), s01); s11 = fmaf(v3, bf_hi(h3.y), s11);
            s02 = fmaf(v3, bf_lo(h3.z), s02); s12 = fmaf(v3, bf_hi(h3.z), s12);
            s03 = fmaf(v3, bf_lo(h3.w), s03); s13 = fmaf(v3, bf_hi(h3.w), s13);
        }
        for (; j < je; ++j) {
            const int2 e0 = ebuf[j];
            const uint4 h0 = *(const uint4*)(H2b + (size_t)(e0.x & 0x1FFFF) * F_HOP);
            const float v0 = __int_as_float(e0.y);
            d += v0;
            s00 = fmaf(v0, bf_lo(h0.x), s00); s10 = fmaf(v0, bf_hi(h0.x), s10);
            s01 = fmaf(v0, bf_lo(h0.y), s01); s11 = fmaf(v0, bf_hi(h0.y), s11);
            s02 = fmaf(v0, bf_lo(h0.z), s02); s12 = fmaf(v0, bf_hi(h0.z), s12);
            s03 = fmaf(v0, bf_lo(h0.w), s03); s13 = fmaf(v0, bf_hi(h0.w), s13);
        }
        // overflow tail (normally empty)
        for (int j2 = ECAP; j2 < m; ++j2) {
            const int2 p = gbuf[bstart + j2];
            if (((p.x >> 17) & (RPB - 1)) == lr) {
                const uint4 h0 = *(const uint4*)(H2b + (size_t)(p.x & 0x1FFFF) * F_HOP);
                const float v0 = __int_as_float(p.y);
                d += v0;
                s00 = fmaf(v0, bf_lo(h0.x), s00); s10 = fmaf(v0, bf_hi(h0.x), s10);
                s01 = fmaf(v0, bf_lo(h0.y), s01); s11 = fmaf(v0, bf_hi(h0.y), s11);
                s02 = fmaf(v0, bf_lo(h0.z), s02); s12 = fmaf(v0, bf_hi(h0.z), s12);
                s03 = fmaf(v0, bf_lo(h0.w), s03); s13 = fmaf(v0, bf_hi(h0.w), s13);
            }
        }

        uint2 tw;
        tw.x = pack_bf16(s10, s11);
        tw.y = pack_bf16(s12, s13);
        *(uint2*)(T16 + (size_t)r * F_HOP + f0) = tw;
        if (l == 0) dg1[r] = d;

        const float inv = (d > 0.f) ? 1.f / d : 0.f;
        const float4 bb4 = *(const float4*)(b0 + f0);
        const float4 ff = *(const float4*)(fc0 + f0);
        const float y0 = s00 * inv + bb4.x;
        const float y1 = s01 * inv + bb4.y;
        const float y2 = s02 * inv + bb4.z;
        const float y3 = s03 * inv + bb4.w;
        float tt = y0 * ff.x + y1 * ff.y + y2 * ff.z + y3 * ff.w;
        #pragma unroll
        for (int mm = 1; mm < 16; mm <<= 1) tt += __shfl_xor(tt, mm, 64);
        const float gg = 1.f / (1.f + __expf(-(tt + bf0[0])));
        float4v o;
        o[0] = fmaxf(y0, 0.f) + gg * fminf(y0, 0.f);
        o[1] = fmaxf(y1, 0.f) + gg * fminf(y1, 0.f);
        o[2] = fmaxf(y2, 0.f) + gg * fminf(y2, 0.f);
        o[3] = fmaxf(y3, 0.f) + gg * fminf(y3, 0.f);
        __builtin_nontemporal_store(o, (float4v*)(out + (size_t)r * F_ALL + f0));
    }
}

// ---------------------------------------------------------------- pass 2 (fused in-LDS sort)
__global__ __launch_bounds__(512) void pass2_kernel(
    const int* __restrict__ bbase, const int2* __restrict__ gbuf,
    const ushort* __restrict__ T16, const float* __restrict__ dg1,
    const float* __restrict__ b1, const float* __restrict__ fc1,
    const float* __restrict__ bf1,
    float* __restrict__ out, int N) {
    __shared__ int2 ebuf[ECAP];
    __shared__ int cnt[RPB];
    __shared__ int rp[RPB + 1];
    __shared__ int wsum2[2];
    const int t = threadIdx.x;
    const int b = blockIdx.x;
    const int bstart = bbase[b];
    const int m = bbase[b + 1] - bstart;
    const int mc = (m < ECAP) ? m : ECAP;
    const int row0 = b << RPB_BITS;

    if (t < RPB) cnt[t] = 0;
    __syncthreads();
    for (int j = t; j < mc; j += 512) {
        const int2 p = gbuf[bstart + j];
        ebuf[j] = p;
        atomicAdd(&cnt[(p.x >> 17) & (RPB - 1)], 1);
    }
    __syncthreads();
    int sv = 0, vv = 0;
    if (t < RPB) {
        sv = cnt[t];
        vv = sv;
        #pragma unroll
        for (int d = 1; d < 64; d <<= 1) {
            int u = __shfl_up(vv, (unsigned)d, 64);
            if ((t & 63) >= d) vv += u;
        }
        if ((t & 63) == 63) wsum2[t >> 6] = vv;
    }
    __syncthreads();
    if (t < RPB) rp[t] = ((t >= 64) ? wsum2[0] : 0) + vv - sv;
    if (t == 0) rp[RPB] = mc;
    __syncthreads();
    if (t < RPB) cnt[t] = rp[t];
    __syncthreads();
    int2 pr[4]; int pp[4]; bool pvld[4];
    #pragma unroll
    for (int k2 = 0; k2 < 4; ++k2) {
        const int j = t + 512 * k2;
        pvld[k2] = (j < mc);
        if (pvld[k2]) {
            pr[k2] = ebuf[j];
            pp[k2] = atomicAdd(&cnt[(pr[k2].x >> 17) & (RPB - 1)], 1);
        }
    }
    __syncthreads();
    #pragma unroll
    for (int k2 = 0; k2 < 4; ++k2)
        if (pvld[k2]) ebuf[pp[k2]] = pr[k2];
    __syncthreads();

    const int l  = t & 15;
    const int g  = t >> 4;
    const int f0 = l * 4;
    const ushort* __restrict__ Tb = T16 + f0;

    for (int k = 0; k < 4; ++k) {
        const int lr = g * 4 + k;
        const int r = row0 + lr;
        if (r >= N) break;
        const int jb = rp[lr], je = rp[lr + 1];

        float s0 = 0.f, s1 = 0.f, s2 = 0.f, s3 = 0.f;
        float d2 = 0.f;
        int j = jb;
        for (; j + 4 <= je; j += 4) {
            const int2 e0 = ebuf[j], e1 = ebuf[j + 1], e2 = ebuf[j + 2], e3 = ebuf[j + 3];
            const int c0i = e0.x & 0x1FFFF, c1i = e1.x & 0x1FFFF;
            const int c2i = e2.x & 0x1FFFF, c3i = e3.x & 0x1FFFF;
            const uint2 t0 = *(const uint2*)(Tb + (size_t)c0i * F_HOP);
            const uint2 t1 = *(const uint2*)(Tb + (size_t)c1i * F_HOP);
            const uint2 t2 = *(const uint2*)(Tb + (size_t)c2i * F_HOP);
            const uint2 t3 = *(const uint2*)(Tb + (size_t)c3i * F_HOP);
            const float g0 = dg1[c0i], g1 = dg1[c1i], g2 = dg1[c2i], g3 = dg1[c3i];
            const float v0 = __int_as_float(e0.y), v1 = __int_as_float(e1.y);
            const float v2 = __int_as_float(e2.y), v3 = __int_as_float(e3.y);
            d2 = fmaf(v0, g0, d2); d2 = fmaf(v1, g1, d2);
            d2 = fmaf(v2, g2, d2); d2 = fmaf(v3, g3, d2);
            s0 = fmaf(v0, bf_lo(t0.x), s0); s1 = fmaf(v0, bf_hi(t0.x), s1);
            s2 = fmaf(v0, bf_lo(t0.y), s2); s3 = fmaf(v0, bf_hi(t0.y), s3);
            s0 = fmaf(v1, bf_lo(t1.x), s0); s1 = fmaf(v1, bf_hi(t1.x), s1);
            s2 = fmaf(v1, bf_lo(t1.y), s2); s3 = fmaf(v1, bf_hi(t1.y), s3);
            s0 = fmaf(v2, bf_lo(t2.x), s0); s1 = fmaf(v2, bf_hi(t2.x), s1);
            s2 = fmaf(v2, bf_lo(t2.y), s2); s3 = fmaf(v2, bf_hi(t2.y), s3);
            s0 = fmaf(v3, bf_lo(t3.x), s0); s1 = fmaf(v3, bf_hi(t3.x), s1);
            s2 = fmaf(v3, bf_lo(t3.y), s2); s3 = fmaf(v3, bf_hi(t3.y), s3);
        }
        for (; j < je; ++j) {
            const int2 e0 = ebuf[j];
            const int c0i = e0.x & 0x1FFFF;
            const uint2 t0 = *(const uint2*)(Tb + (size_t)c0i * F_HOP);
            const float v0 = __int_as_float(e0.y);
            d2 = fmaf(v0, dg1[c0i], d2);
            s0 = fmaf(v0, bf_lo(t0.x), s0); s1 = fmaf(v0, bf_hi(t0.x), s1);
            s2 = fmaf(v0, bf_lo(t0.y), s2); s3 = fmaf(v0, bf_hi(t0.y), s3);
        }
        for (int j2 = ECAP; j2 < m; ++j2) {
            const int2 p = gbuf[bstart + j2];
            if (((p.x >> 17) & (RPB - 1)) == lr) {
                const int c0i = p.x & 0x1FFFF;
                const uint2 t0 = *(const uint2*)(Tb + (size_t)c0i * F_HOP);
                const float v0 = __int_as_float(p.y);
                d2 = fmaf(v0, dg1[c0i], d2);
                s0 = fmaf(v0, bf_lo(t0.x), s0); s1 = fmaf(v0, bf_hi(t0.x), s1);
                s2 = fmaf(v0, bf_lo(t0.y), s2); s3 = fmaf(v0, bf_hi(t0.y), s3);
            }
        }

        const float inv = (d2 > 0.f) ? 1.f / d2 : 0.f;
        const float4 bb4 = *(const float4*)(b1 + f0);
        const float4 ff = *(const float4*)(fc1 + f0);
        const float y0 = s0 * inv + bb4.x;
        const float y1 = s1 * inv + bb4.y;
        const float y2 = s2 * inv + bb4.z;
        const float y3 = s3 * inv + bb4.w;
        float tt = y0 * ff.x + y1 * ff.y + y2 * ff.z + y3 * ff.w;
        #pragma unroll
        for (int mm = 1; mm < 16; mm <<= 1) tt += __shfl_xor(tt, mm, 64);
        const float gg = 1.f / (1.f + __expf(-(tt + bf1[0])));
        float4v o;
        o[0] = fmaxf(y0, 0.f) + gg * fminf(y0, 0.f);
        o[1] = fmaxf(y1, 0.f) + gg * fminf(y1, 0.f);
        o[2] = fmaxf(y2, 0.f) + gg * fminf(y2, 0.f);
        o[3] = fmaxf(y3, 0.f) + gg * fminf(y3, 0.f);
        __builtin_nontemporal_store(o, (float4v*)(out + (size_t)r * F_ALL + F_HOP + f0));
    }
}

// ---------------------------------------------------------------- launch
extern "C" void kernel_launch(void* const* d_in, const int* in_sizes, int n_in,
                              void* d_out, int out_size, void* d_ws, size_t ws_size,
                              hipStream_t stream) {
    const float* x   = (const float*)d_in[0];
    const int*   ei  = (const int*)  d_in[1];
    const float* ea  = (const float*)d_in[2];
    const float* W0  = (const float*)d_in[3];
    const float* b0  = (const float*)d_in[4];
    const float* W1  = (const float*)d_in[5];
    const float* b1  = (const float*)d_in[6];
    const float* fc0 = (const float*)d_in[7];
    const float* bf0 = (const float*)d_in[8];
    const float* fc1 = (const float*)d_in[9];
    const float* bf1 = (const float*)d_in[10];
    float* out = (float*)d_out;

    const int N = in_sizes[0] / F_IN;
    const int E = in_sizes[2];
    const int K = (N + RPB - 1) >> RPB_BITS;   // coarse buckets (<= KB_MAX)

    // workspace layout (4-byte units, regions 16B-aligned)
    uint*   H2   = (uint*)d_ws;                                  // N*64
    ushort* T16  = (ushort*)(H2 + (size_t)N * F_HOP);            // N*64 u16
    float*  dg1  = (float*)(T16 + (size_t)N * F_HOP);            // N
    int2*   gbuf = (int2*)(dg1 + (size_t)((N + 3) & ~3));        // E (bucketed edges)
    int*    bhist = (int*)(gbuf + (size_t)E);                    // NBLK_BIN*KB_MAX
    int*    btot  = bhist + (size_t)NBLK_BIN * KB_MAX;           // K
    int*    bbase = btot + (KB_MAX + 4);                         // K+1

    const int gemmBlocks = (N + 63) / 64;
    gemm_hist_kernel<<<gemmBlocks + NBLK_BIN, 256, 0, stream>>>(
        x, W0, W1, H2, ei, bhist, N, E, K, gemmBlocks);

    blockscan_kernel<<<K, 512, 0, stream>>>(bhist, btot);
    bin_kernel<<<NBLK_BIN, 256, 0, stream>>>(ei, ea, bhist, btot, bbase, gbuf, E, K);

    pass1_kernel<<<K, 512, 0, stream>>>(
        bbase, gbuf, H2, b0, fc0, bf0, out, T16, dg1, N);

    pass2_kernel<<<K, 512, 0, stream>>>(
        bbase, gbuf, T16, dg1, b1, fc1, bf1, out, N);
}

// Round 8
// 234.177 us; speedup vs baseline: 1.0272x; 1.0272x over previous
//
#include <hip/hip_runtime.h>

#define F_IN 128
#define F_ALL 128
#define F_HOP 64

#define RPB_BITS 6
#define RPB 64             // rows per bucket
#define KB_MAX 2048        // max buckets (N <= 131072)
#define NBLK_BUILD 256     // build blocks fused into gemm kernel
#define CAP 1024           // fixed gbuf slots per bucket (mean 640 at E=1M,K=1563; +15 sigma)
#define OVF_CAP 65536      // overflow entries (normally 0 used)

typedef unsigned int uint;
typedef unsigned short ushort;
typedef __attribute__((ext_vector_type(8))) short short8v;
typedef __attribute__((ext_vector_type(4))) float float4v;

// ---------------------------------------------------------------- helpers
__device__ __forceinline__ uint pack_bf16(float lo, float hi) {
    uint ul = __float_as_uint(lo), uh = __float_as_uint(hi);
    ul += 0x7FFFu + ((ul >> 16) & 1u);
    uh += 0x7FFFu + ((uh >> 16) & 1u);
    return (ul >> 16) | (uh & 0xFFFF0000u);
}
__device__ __forceinline__ float bf_lo(uint h) { return __uint_as_float(h << 16); }
__device__ __forceinline__ float bf_hi(uint h) { return __uint_as_float(h & 0xFFFF0000u); }

// ---------------------------------------------------------------- kernel 1: fused MFMA GEMM + edge binning
// Build blocks (blockIdx < NBLK_BUILD) bin edges into fixed-capacity bucket regions:
//   LDS hist of chunk -> one global atomicAdd per (block,bucket) to reserve -> scatter.
// Gemm blocks follow and overlap (independent inputs).
// payload: word0 = col | (r_local << 17), word1 = val fp32
__global__ __launch_bounds__(256) void gemm_build_kernel(
    const float* __restrict__ x, const float* __restrict__ W0,
    const float* __restrict__ W1, uint* __restrict__ H2,
    const int* __restrict__ ei, const float* __restrict__ ea,
    int* __restrict__ gcnt,          // K counters, padded stride 16 ints (64 B)
    int* __restrict__ ovfCnt, int4* __restrict__ ovf,
    int2* __restrict__ gbuf, int N, int E, int K) {
    __shared__ ushort Wlds[16384];    // 32 KB (gemm); build aliases h[] + cur[]

    const int t = threadIdx.x;
    if ((int)blockIdx.x < NBLK_BUILD) {
        // ---------------- build branch
        int* h   = (int*)Wlds;        // [KB_MAX]
        int* cur = h + KB_MAX;        // [KB_MAX]
        const int hb = blockIdx.x;
        for (int i = t; i < K; i += 256) h[i] = 0;
        __syncthreads();
        const int chunk = (E + NBLK_BUILD - 1) / NBLK_BUILD;
        const int s = hb * chunk;
        const int e = min(s + chunk, E);
        for (int j = s + t; j < e; j += 256)
            atomicAdd(&h[__builtin_nontemporal_load(ei + j) >> RPB_BITS], 1);
        __syncthreads();
        for (int b = t; b < K; b += 256) {
            const int hc = h[b];
            if (hc) cur[b] = atomicAdd(&gcnt[b * 16], hc);   // reserve bucket-relative range
        }
        __syncthreads();
        for (int j = s + t; j < e; j += 256) {
            const int r = ei[j];                              // L2-hot re-read
            const int c = ei[E + j];
            const int vv = __float_as_int(ea[j]);
            const int b = r >> RPB_BITS;
            const int w0 = c | ((r & (RPB - 1)) << 17);
            const int pos = atomicAdd(&cur[b], 1);
            if (pos < CAP) {
                gbuf[(size_t)b * CAP + pos] = make_int2(w0, vv);
            } else {
                const int op = atomicAdd(ovfCnt, 1);
                if (op < OVF_CAP) ovf[op] = make_int4(b, w0, vv, 0);
            }
        }
        return;
    }

    // ---------------- gemm branch
    {
        #pragma unroll
        for (int i = 0; i < 8; ++i) {
            const int e    = t + 256 * i;
            const int lane = e & 63;
            const int tile = e >> 6;
            const int kt   = tile >> 3;
            const int nt   = tile & 7;
            const int k0   = kt * 32 + (lane >> 4) * 8;
            const int n    = nt * 16 + (lane & 15);
            const float* src = (n < 64) ? (W0 + n) : (W1 + (n - 64));
            float v[8];
            #pragma unroll
            for (int j = 0; j < 8; ++j) v[j] = src[(size_t)(k0 + j) * F_HOP];
            uint4 o;
            o.x = pack_bf16(v[0], v[1]);
            o.y = pack_bf16(v[2], v[3]);
            o.z = pack_bf16(v[4], v[5]);
            o.w = pack_bf16(v[6], v[7]);
            *((uint4*)Wlds + e) = o;
        }
    }
    __syncthreads();

    const int wv   = t >> 6;
    const int lane = t & 63;
    const int rbase = (blockIdx.x - NBLK_BUILD) * 64 + wv * 16;
    if (rbase >= N) return;

    const int m    = lane & 15;
    const int quad = lane >> 4;
    const float* xrow = x + (size_t)(rbase + m) * F_IN + quad * 8;

    float4v acc[8];
    #pragma unroll
    for (int tt = 0; tt < 8; ++tt) acc[tt] = (float4v){0.f, 0.f, 0.f, 0.f};

    #pragma unroll
    for (int kt = 0; kt < 4; ++kt) {
        const float4v xa = __builtin_nontemporal_load((const float4v*)(xrow + kt * 32));
        const float4v xb = __builtin_nontemporal_load((const float4v*)(xrow + kt * 32 + 4));
        union { uint4 u; short8v s; } av;
        av.u.x = pack_bf16(xa[0], xa[1]);
        av.u.y = pack_bf16(xa[2], xa[3]);
        av.u.z = pack_bf16(xb[0], xb[1]);
        av.u.w = pack_bf16(xb[2], xb[3]);
        #pragma unroll
        for (int nt = 0; nt < 8; ++nt) {
            union { uint4 u; short8v s; } bv;
            bv.u = *((const uint4*)Wlds + (kt * 8 + nt) * 64 + lane);
            acc[nt] = __builtin_amdgcn_mfma_f32_16x16x32_bf16(av.s, bv.s, acc[nt], 0, 0, 0);
        }
    }

    #pragma unroll
    for (int tt = 0; tt < 4; ++tt) {
        #pragma unroll
        for (int i = 0; i < 4; ++i) {
            const int r = rbase + quad * 4 + i;
            H2[(size_t)r * F_HOP + tt * 16 + m] = pack_bf16(acc[tt][i], acc[tt + 4][i]);
        }
    }
}

// ---------------------------------------------------------------- kernel 2: pass 1 (in-LDS sort + gather)
// One 256-thread block per bucket (64 rows). Load bucket region to LDS, count/scan/place by
// local row, then per-row gather (16 lanes/row, uint4/lane -> 16 edge-gathers in flight/wave).
__global__ __launch_bounds__(256) void pass1_kernel(
    const int* __restrict__ gcnt, const int2* __restrict__ gbuf,
    const int* __restrict__ ovfCnt, const int4* __restrict__ ovf,
    const uint* __restrict__ H2,
    const float* __restrict__ b0, const float* __restrict__ fc0,
    const float* __restrict__ bf0,
    float* __restrict__ out, ushort* __restrict__ T16,
    float* __restrict__ dg1, int N) {
    __shared__ int2 ebuf[CAP];       // 8 KB
    __shared__ int cnt[RPB];
    __shared__ int rp[RPB + 1];
    const int t = threadIdx.x;
    const int b = blockIdx.x;
    const int cntb = gcnt[b * 16];
    const int mc = (cntb < CAP) ? cntb : CAP;
    const int ovfn = (cntb > CAP) ? min(*ovfCnt, OVF_CAP) : 0;
    const int row0 = b << RPB_BITS;
    const int2* __restrict__ gb = gbuf + (size_t)b * CAP;

    if (t < RPB) cnt[t] = 0;
    __syncthreads();
    for (int j = t; j < mc; j += 256) {
        const int2 p = gb[j];
        ebuf[j] = p;
        atomicAdd(&cnt[(p.x >> 17) & (RPB - 1)], 1);
    }
    __syncthreads();
    if (t < RPB) {                    // single-wave 64-wide scan
        const int sv = cnt[t];
        int vv = sv;
        #pragma unroll
        for (int d = 1; d < 64; d <<= 1) {
            int u = __shfl_up(vv, (unsigned)d, 64);
            if (t >= d) vv += u;
        }
        rp[t] = vv - sv;
        if (t == RPB - 1) rp[RPB] = mc;
    }
    __syncthreads();
    if (t < RPB) cnt[t] = rp[t];      // placement cursor
    __syncthreads();
    int2 pr[4]; int pp[4]; bool pvld[4];
    #pragma unroll
    for (int k2 = 0; k2 < 4; ++k2) {
        const int j = t + 256 * k2;
        pvld[k2] = (j < mc);
        if (pvld[k2]) {
            pr[k2] = ebuf[j];
            pp[k2] = atomicAdd(&cnt[(pr[k2].x >> 17) & (RPB - 1)], 1);
        }
    }
    __syncthreads();
    #pragma unroll
    for (int k2 = 0; k2 < 4; ++k2)
        if (pvld[k2]) ebuf[pp[k2]] = pr[k2];
    __syncthreads();

    const int l  = t & 15;
    const int g  = t >> 4;            // 0..15 row-groups per block
    const int f0 = l * 4;
    const uint* __restrict__ H2b = H2 + f0;

    for (int k = 0; k < 4; ++k) {
        const int lr = g * 4 + k;
        const int r = row0 + lr;
        if (r >= N) break;
        const int jb = rp[lr], je = rp[lr + 1];

        float s00 = 0.f, s01 = 0.f, s02 = 0.f, s03 = 0.f;   // hop0 (lo)
        float s10 = 0.f, s11 = 0.f, s12 = 0.f, s13 = 0.f;   // hop1 (hi)
        float d = 0.f;
        int j = jb;
        for (; j + 4 <= je; j += 4) {
            const int2 e0 = ebuf[j], e1 = ebuf[j + 1], e2 = ebuf[j + 2], e3 = ebuf[j + 3];
            const uint4 h0 = *(const uint4*)(H2b + (size_t)(e0.x & 0x1FFFF) * F_HOP);
            const uint4 h1 = *(const uint4*)(H2b + (size_t)(e1.x & 0x1FFFF) * F_HOP);
            const uint4 h2 = *(const uint4*)(H2b + (size_t)(e2.x & 0x1FFFF) * F_HOP);
            const uint4 h3 = *(const uint4*)(H2b + (size_t)(e3.x & 0x1FFFF) * F_HOP);
            const float v0 = __int_as_float(e0.y), v1 = __int_as_float(e1.y);
            const float v2 = __int_as_float(e2.y), v3 = __int_as_float(e3.y);
            d += (v0 + v1) + (v2 + v3);
            s00 = fmaf(v0, bf_lo(h0.x), s00); s10 = fmaf(v0, bf_hi(h0.x), s10);
            s01 = fmaf(v0, bf_lo(h0.y), s01); s11 = fmaf(v0, bf_hi(h0.y), s11);
            s02 = fmaf(v0, bf_lo(h0.z), s02); s12 = fmaf(v0, bf_hi(h0.z), s12);
            s03 = fmaf(v0, bf_lo(h0.w), s03); s13 = fmaf(v0, bf_hi(h0.w), s13);
            s00 = fmaf(v1, bf_lo(h1.x), s00); s10 = fmaf(v1, bf_hi(h1.x), s10);
            s01 = fmaf(v1, bf_lo(h1.y), s01); s11 = fmaf(v1, bf_hi(h1.y), s11);
            s02 = fmaf(v1, bf_lo(h1.z), s02); s12 = fmaf(v1, bf_hi(h1.z), s12);
            s03 = fmaf(v1, bf_lo(h1.w), s03); s13 = fmaf(v1, bf_hi(h1.w), s13);
            s00 = fmaf(v2, bf_lo(h2.x), s00); s10 = fmaf(v2, bf_hi(h2.x), s10);
            s01 = fmaf(v2, bf_lo(h2.y), s01); s11 = fmaf(v2, bf_hi(h2.y), s11);
            s02 = fmaf(v2, bf_lo(h2.z), s02); s12 = fmaf(v2, bf_hi(h2.z), s12);
            s03 = fmaf(v2, bf_lo(h2.w), s03); s13 = fmaf(v2, bf_hi(h2.w), s13);
            s00 = fmaf(v3, bf_lo(h3.x), s00); s10 = fmaf(v3, bf_hi(h3.x), s10);
            s01 = fmaf(v3, bf_lo(h3.y), s01); s11 = fmaf(v3, bf_hi(h3.y), s11);
            s02 = fmaf(v3, bf_lo(h3.z), s02); s12 = fmaf(v3, bf_hi(h3.z), s12);
            s03 = fmaf(v3, bf_lo(h3.w), s03); s13 = fmaf(v3, bf_hi(h3.w), s13);
        }
        for (; j < je; ++j) {
            const int2 e0 = ebuf[j];
            const uint4 h0 = *(const uint4*)(H2b + (size_t)(e0.x & 0x1FFFF) * F_HOP);
            const float v0 = __int_as_float(e0.y);
            d += v0;
            s00 = fmaf(v0, bf_lo(h0.x), s00); s10 = fmaf(v0, bf_hi(h0.x), s10);
            s01 = fmaf(v0, bf_lo(h0.y), s01); s11 = fmaf(v0, bf_hi(h0.y), s11);
            s02 = fmaf(v0, bf_lo(h0.z), s02); s12 = fmaf(v0, bf_hi(h0.z), s12);
            s03 = fmaf(v0, bf_lo(h0.w), s03); s13 = fmaf(v0, bf_hi(h0.w), s13);
        }
        // overflow tail (normally empty)
        for (int j2 = 0; j2 < ovfn; ++j2) {
            const int4 p = ovf[j2];
            if (p.x == b && (((p.y >> 17) & (RPB - 1)) == lr)) {
                const uint4 h0 = *(const uint4*)(H2b + (size_t)(p.y & 0x1FFFF) * F_HOP);
                const float v0 = __int_as_float(p.z);
                d += v0;
                s00 = fmaf(v0, bf_lo(h0.x), s00); s10 = fmaf(v0, bf_hi(h0.x), s10);
                s01 = fmaf(v0, bf_lo(h0.y), s01); s11 = fmaf(v0, bf_hi(h0.y), s11);
                s02 = fmaf(v0, bf_lo(h0.z), s02); s12 = fmaf(v0, bf_hi(h0.z), s12);
                s03 = fmaf(v0, bf_lo(h0.w), s03); s13 = fmaf(v0, bf_hi(h0.w), s13);
            }
        }

        uint2 tw;
        tw.x = pack_bf16(s10, s11);
        tw.y = pack_bf16(s12, s13);
        *(uint2*)(T16 + (size_t)r * F_HOP + f0) = tw;
        if (l == 0) dg1[r] = d;

        const float inv = (d > 0.f) ? 1.f / d : 0.f;
        const float4 bb4 = *(const float4*)(b0 + f0);
        const float4 ff = *(const float4*)(fc0 + f0);
        const float y0 = s00 * inv + bb4.x;
        const float y1 = s01 * inv + bb4.y;
        const float y2 = s02 * inv + bb4.z;
        const float y3 = s03 * inv + bb4.w;
        float tt = y0 * ff.x + y1 * ff.y + y2 * ff.z + y3 * ff.w;
        #pragma unroll
        for (int mm = 1; mm < 16; mm <<= 1) tt += __shfl_xor(tt, mm, 64);
        const float gg = 1.f / (1.f + __expf(-(tt + bf0[0])));
        float4v o;
        o[0] = fmaxf(y0, 0.f) + gg * fminf(y0, 0.f);
        o[1] = fmaxf(y1, 0.f) + gg * fminf(y1, 0.f);
        o[2] = fmaxf(y2, 0.f) + gg * fminf(y2, 0.f);
        o[3] = fmaxf(y3, 0.f) + gg * fminf(y3, 0.f);
        __builtin_nontemporal_store(o, (float4v*)(out + (size_t)r * F_ALL + f0));
    }
}

// ---------------------------------------------------------------- kernel 3: pass 2 (in-LDS sort + gather)
__global__ __launch_bounds__(256) void pass2_kernel(
    const int* __restrict__ gcnt, const int2* __restrict__ gbuf,
    const int* __restrict__ ovfCnt, const int4* __restrict__ ovf,
    const ushort* __restrict__ T16, const float* __restrict__ dg1,
    const float* __restrict__ b1, const float* __restrict__ fc1,
    const float* __restrict__ bf1,
    float* __restrict__ out, int N) {
    __shared__ int2 ebuf[CAP];
    __shared__ int cnt[RPB];
    __shared__ int rp[RPB + 1];
    const int t = threadIdx.x;
    const int b = blockIdx.x;
    const int cntb = gcnt[b * 16];
    const int mc = (cntb < CAP) ? cntb : CAP;
    const int ovfn = (cntb > CAP) ? min(*ovfCnt, OVF_CAP) : 0;
    const int row0 = b << RPB_BITS;
    const int2* __restrict__ gb = gbuf + (size_t)b * CAP;

    if (t < RPB) cnt[t] = 0;
    __syncthreads();
    for (int j = t; j < mc; j += 256) {
        const int2 p = gb[j];
        ebuf[j] = p;
        atomicAdd(&cnt[(p.x >> 17) & (RPB - 1)], 1);
    }
    __syncthreads();
    if (t < RPB) {
        const int sv = cnt[t];
        int vv = sv;
        #pragma unroll
        for (int d = 1; d < 64; d <<= 1) {
            int u = __shfl_up(vv, (unsigned)d, 64);
            if (t >= d) vv += u;
        }
        rp[t] = vv - sv;
        if (t == RPB - 1) rp[RPB] = mc;
    }
    __syncthreads();
    if (t < RPB) cnt[t] = rp[t];
    __syncthreads();
    int2 pr[4]; int pp[4]; bool pvld[4];
    #pragma unroll
    for (int k2 = 0; k2 < 4; ++k2) {
        const int j = t + 256 * k2;
        pvld[k2] = (j < mc);
        if (pvld[k2]) {
            pr[k2] = ebuf[j];
            pp[k2] = atomicAdd(&cnt[(pr[k2].x >> 17) & (RPB - 1)], 1);
        }
    }
    __syncthreads();
    #pragma unroll
    for (int k2 = 0; k2 < 4; ++k2)
        if (pvld[k2]) ebuf[pp[k2]] = pr[k2];
    __syncthreads();

    const int l  = t & 15;
    const int g  = t >> 4;
    const int f0 = l * 4;
    const ushort* __restrict__ Tb = T16 + f0;

    for (int k = 0; k < 4; ++k) {
        const int lr = g * 4 + k;
        const int r = row0 + lr;
        if (r >= N) break;
        const int jb = rp[lr], je = rp[lr + 1];

        float s0 = 0.f, s1 = 0.f, s2 = 0.f, s3 = 0.f;
        float d2 = 0.f;
        int j = jb;
        for (; j + 4 <= je; j += 4) {
            const int2 e0 = ebuf[j], e1 = ebuf[j + 1], e2 = ebuf[j + 2], e3 = ebuf[j + 3];
            const int c0i = e0.x & 0x1FFFF, c1i = e1.x & 0x1FFFF;
            const int c2i = e2.x & 0x1FFFF, c3i = e3.x & 0x1FFFF;
            const uint2 t0 = *(const uint2*)(Tb + (size_t)c0i * F_HOP);
            const uint2 t1 = *(const uint2*)(Tb + (size_t)c1i * F_HOP);
            const uint2 t2 = *(const uint2*)(Tb + (size_t)c2i * F_HOP);
            const uint2 t3 = *(const uint2*)(Tb + (size_t)c3i * F_HOP);
            const float g0 = dg1[c0i], g1 = dg1[c1i], g2 = dg1[c2i], g3 = dg1[c3i];
            const float v0 = __int_as_float(e0.y), v1 = __int_as_float(e1.y);
            const float v2 = __int_as_float(e2.y), v3 = __int_as_float(e3.y);
            d2 = fmaf(v0, g0, d2); d2 = fmaf(v1, g1, d2);
            d2 = fmaf(v2, g2, d2); d2 = fmaf(v3, g3, d2);
            s0 = fmaf(v0, bf_lo(t0.x), s0); s1 = fmaf(v0, bf_hi(t0.x), s1);
            s2 = fmaf(v0, bf_lo(t0.y), s2); s3 = fmaf(v0, bf_hi(t0.y), s3);
            s0 = fmaf(v1, bf_lo(t1.x), s0); s1 = fmaf(v1, bf_hi(t1.x), s1);
            s2 = fmaf(v1, bf_lo(t1.y), s2); s3 = fmaf(v1, bf_hi(t1.y), s3);
            s0 = fmaf(v2, bf_lo(t2.x), s0); s1 = fmaf(v2, bf_hi(t2.x), s1);
            s2 = fmaf(v2, bf_lo(t2.y), s2); s3 = fmaf(v2, bf_hi(t2.y), s3);
            s0 = fmaf(v3, bf_lo(t3.x), s0); s1 = fmaf(v3, bf_hi(t3.x), s1);
            s2 = fmaf(v3, bf_lo(t3.y), s2); s3 = fmaf(v3, bf_hi(t3.y), s3);
        }
        for (; j < je; ++j) {
            const int2 e0 = ebuf[j];
            const int c0i = e0.x & 0x1FFFF;
            const uint2 t0 = *(const uint2*)(Tb + (size_t)c0i * F_HOP);
            const float v0 = __int_as_float(e0.y);
            d2 = fmaf(v0, dg1[c0i], d2);
            s0 = fmaf(v0, bf_lo(t0.x), s0); s1 = fmaf(v0, bf_hi(t0.x), s1);
            s2 = fmaf(v0, bf_lo(t0.y), s2); s3 = fmaf(v0, bf_hi(t0.y), s3);
        }
        for (int j2 = 0; j2 < ovfn; ++j2) {
            const int4 p = ovf[j2];
            if (p.x == b && (((p.y >> 17) & (RPB - 1)) == lr)) {
                const int c0i = p.y & 0x1FFFF;
                const uint2 t0 = *(const uint2*)(Tb + (size_t)c0i * F_HOP);
                const float v0 = __int_as_float(p.z);
                d2 = fmaf(v0, dg1[c0i], d2);
                s0 = fmaf(v0, bf_lo(t0.x), s0); s1 = fmaf(v0, bf_hi(t0.x), s1);
                s2 = fmaf(v0, bf_lo(t0.y), s2); s3 = fmaf(v0, bf_hi(t0.y), s3);
            }
        }

        const float inv = (d2 > 0.f) ? 1.f / d2 : 0.f;
        const float4 bb4 = *(const float4*)(b1 + f0);
        const float4 ff = *(const float4*)(fc1 + f0);
        const float y0 = s0 * inv + bb4.x;
        const float y1 = s1 * inv + bb4.y;
        const float y2 = s2 * inv + bb4.z;
        const float y3 = s3 * inv + bb4.w;
        float tt = y0 * ff.x + y1 * ff.y + y2 * ff.z + y3 * ff.w;
        #pragma unroll
        for (int mm = 1; mm < 16; mm <<= 1) tt += __shfl_xor(tt, mm, 64);
        const float gg = 1.f / (1.f + __expf(-(tt + bf1[0])));
        float4v o;
        o[0] = fmaxf(y0, 0.f) + gg * fminf(y0, 0.f);
        o[1] = fmaxf(y1, 0.f) + gg * fminf(y1, 0.f);
        o[2] = fmaxf(y2, 0.f) + gg * fminf(y2, 0.f);
        o[3] = fmaxf(y3, 0.f) + gg * fminf(y3, 0.f);
        __builtin_nontemporal_store(o, (float4v*)(out + (size_t)r * F_ALL + F_HOP + f0));
    }
}

// ---------------------------------------------------------------- launch
extern "C" void kernel_launch(void* const* d_in, const int* in_sizes, int n_in,
                              void* d_out, int out_size, void* d_ws, size_t ws_size,
                              hipStream_t stream) {
    const float* x   = (const float*)d_in[0];
    const int*   ei  = (const int*)  d_in[1];
    const float* ea  = (const float*)d_in[2];
    const float* W0  = (const float*)d_in[3];
    const float* b0  = (const float*)d_in[4];
    const float* W1  = (const float*)d_in[5];
    const float* b1  = (const float*)d_in[6];
    const float* fc0 = (const float*)d_in[7];
    const float* bf0 = (const float*)d_in[8];
    const float* fc1 = (const float*)d_in[9];
    const float* bf1 = (const float*)d_in[10];
    float* out = (float*)d_out;

    const int N = in_sizes[0] / F_IN;
    const int E = in_sizes[2];
    const int K = (N + RPB - 1) >> RPB_BITS;   // buckets (<= KB_MAX)

    // workspace layout (4-byte units, regions 16B-aligned)
    uint*   H2   = (uint*)d_ws;                                  // N*64
    ushort* T16  = (ushort*)(H2 + (size_t)N * F_HOP);            // N*64 u16
    float*  dg1  = (float*)(T16 + (size_t)N * F_HOP);            // N
    int*    gcnt = (int*)(dg1 + (size_t)((N + 3) & ~3));         // K*16 (padded counters)
    int*    ovfCnt = gcnt + (size_t)K * 16;                      // 1 (+15 pad)
    int2*   gbuf = (int2*)(ovfCnt + 16);                         // K*CAP
    int4*   ovf  = (int4*)(gbuf + (size_t)K * CAP);              // OVF_CAP

    hipMemsetAsync(gcnt, 0, ((size_t)K * 16 + 16) * sizeof(int), stream);

    const int gemmBlocks = (N + 63) / 64;
    gemm_build_kernel<<<NBLK_BUILD + gemmBlocks, 256, 0, stream>>>(
        x, W0, W1, H2, ei, ea, gcnt, ovfCnt, ovf, gbuf, N, E, K);

    pass1_kernel<<<K, 256, 0, stream>>>(
        gcnt, gbuf, ovfCnt, ovf, H2, b0, fc0, bf0, out, T16, dg1, N);

    pass2_kernel<<<K, 256, 0, stream>>>(
        gcnt, gbuf, ovfCnt, ovf, T16, dg1, b1, fc1, bf1, out, N);
}